// Round 13
// baseline (358.788 us; speedup 1.0000x reference)
//
#include <hip/hip_runtime.h>
#include <stdint.h>

#define S_LEN 2048
#define EMB   2560
#define NH    32
#define HD    80
#define DP    96   // padded head dim for Q,K (3 x 32)

typedef __bf16 bf16x8 __attribute__((ext_vector_type(8)));
typedef float  f32x4  __attribute__((ext_vector_type(4)));

__device__ __forceinline__ ushort f2bf(float x) {
    union { float f; uint32_t u; } v; v.f = x;
    return (ushort)((v.u + 0x7FFFu + ((v.u >> 16) & 1u)) >> 16);
}

__device__ __forceinline__ bf16x8 ldg8(const ushort* p) {
    return *reinterpret_cast<const bf16x8*>(p);
}

__device__ __forceinline__ void gload_lds16(const void* g, void* l) {
    __builtin_amdgcn_global_load_lds((__attribute__((address_space(1))) void*)g,
                                     (__attribute__((address_space(3))) void*)l,
                                     16, 0, 0);
}

__device__ __forceinline__ void gload_lds4(const void* g, void* l) {
    __builtin_amdgcn_global_load_lds((__attribute__((address_space(1))) void*)g,
                                     (__attribute__((address_space(3))) void*)l,
                                     4, 0, 0);
}

// ---------------- elementwise f32 -> bf16 ----------------
__global__ void cvt_f32_bf16(const float* __restrict__ in, ushort* __restrict__ out, int n4) {
    int i = blockIdx.x * blockDim.x + threadIdx.x;
    if (i >= n4) return;
    float4 v = reinterpret_cast<const float4*>(in)[i];
    ushort4 r;
    r.x = f2bf(v.x); r.y = f2bf(v.y); r.z = f2bf(v.z); r.w = f2bf(v.w);
    reinterpret_cast<ushort4*>(out)[i] = r;
}

// ---------------- zero the pad columns (d=80..95) of Q and K ----------------
__global__ void pad_zero(ushort* __restrict__ Qb, ushort* __restrict__ Kb) {
    int i   = blockIdx.x * blockDim.x + threadIdx.x;   // 131072 threads
    int row = i & 65535;
    ushort* base = ((i >> 16) ? Kb : Qb) + (size_t)row * DP + HD;
    uint4 z = {0, 0, 0, 0};
    *reinterpret_cast<uint4*>(base)     = z;
    *reinterpret_cast<uint4*>(base + 8) = z;
}

// ---------------- transpose f32 [R][C] -> bf16 [C][R] ----------------
__global__ void transpose_cvt(const float* __restrict__ in, ushort* __restrict__ out, int R, int C) {
    __shared__ float tile[32][33];
    const int bx = blockIdx.x << 5;
    const int by = blockIdx.y << 5;
    const int tx = threadIdx.x, ty = threadIdx.y;  // (32,8)
#pragma unroll
    for (int i = 0; i < 4; ++i)
        tile[ty + 8 * i][tx] = in[(size_t)(by + ty + 8 * i) * C + bx + tx];
    __syncthreads();
#pragma unroll
    for (int i = 0; i < 4; ++i)
        out[(size_t)(bx + ty + 8 * i) * R + by + tx] = f2bf(tile[tx][ty + 8 * i]);
}

// ================= 8-phase GEMM (shared main loop) =================
// A[M][2560] x BT[N][2560]. BM=128, BN=256, BK=64; 512 threads = 8 waves.
// 3 rotating LDS slots, prefetch distance 2 K-tiles, counted vmcnt(6).
// EPI==0: QKV scatter epilogue (N=7680). EPI==1: fp32 C + bias (proj).
#define MF(a, b, c) __builtin_amdgcn_mfma_f32_16x16x32_bf16((a), (b), (c), 0, 0, 0)

#define STAGE(kt2, j) do {                                                          \
    char* _d = Lds + ((kt2) % 3) * 49152 + ldsW[(j)];                               \
    if ((j) < 2) gload_lds16(aG + (size_t)(kt2) * 128 + srcA[(j)], _d);             \
    else         gload_lds16(bG + (size_t)(kt2) * 128 + srcB[(j) - 2], _d);         \
} while (0)

#define LDA(mi, kk) (*(const bf16x8*)(sbase + ((wr * 64 + (mi) * 16 + lo) * 128 +   \
                      ((((kk) * 64) + hi * 16) ^ ((lo & 7) << 4)))))
#define LDB(ni, kk) (*(const bf16x8*)(sbase + 16384 +                               \
                      ((wc * 64 + (ni) * 16 + lo) * 128 +                           \
                      ((((kk) * 64) + hi * 16) ^ ((lo & 7) << 4)))))

template <int EPI>
__global__ __launch_bounds__(512)
void gemm8p(const ushort* __restrict__ A, const ushort* __restrict__ BT,
            int nbn, const float* __restrict__ bvec,
            ushort* __restrict__ Qo, ushort* __restrict__ Ko, ushort* __restrict__ Vo,
            float* __restrict__ Co, int Ncols)
{
    __shared__ char Lds[3 * 49152];   // 147456 B

    const int NT  = 40;               // 2560 / 64
    const int bid = blockIdx.x;
    const int cpx = gridDim.x >> 3;   // grid % 8 == 0
    const int wg  = (bid & 7) * cpx + (bid >> 3);   // bijective XCD swizzle
    const int bm  = wg / nbn, bn = wg - bm * nbn;

    const int tid = threadIdx.x, w = tid >> 6, lane = tid & 63;
    const int lo  = lane & 15, hi = lane >> 4;
    const int wr  = w >> 2, wc = w & 3;

    const char* aG = (const char*)(A  + (size_t)bm * 128 * 2560);
    const char* bG = (const char*)(BT + (size_t)bn * 256 * 2560);

    int srcA[2], srcB[4], ldsW[6];
#pragma unroll
    for (int j = 0; j < 6; ++j) {
        int Lb = j * 8192 + w * 1024 + lane * 16;
        ldsW[j] = j * 8192 + w * 1024;
        int y = Lb & 127;
        if (j < 2) {
            int r = Lb >> 7;
            srcA[j] = r * 5120 + (y ^ ((r & 7) << 4));
        } else {
            int r = (Lb - 16384) >> 7;
            srcB[j - 2] = r * 5120 + (y ^ ((r & 7) << 4));
        }
    }

    f32x4  acc[4][4] = {};
    bf16x8 Afr[2][2], Bfr[4][2];

#pragma unroll
    for (int j = 0; j < 6; ++j) STAGE(0, j);
#pragma unroll
    for (int j = 0; j < 6; ++j) STAGE(1, j);

#pragma unroll 1
    for (int t = 0; t < NT; ++t) {
        const char* sbase = Lds + (t % 3) * 49152;
        const int  t2 = t + 2;
        const bool pf = (t2 < NT);

        if (t < NT - 1) asm volatile("s_waitcnt vmcnt(6)" ::: "memory");
        else            asm volatile("s_waitcnt vmcnt(0)" ::: "memory");
        __builtin_amdgcn_s_barrier();

        // ---- phase 0
        Afr[0][0] = LDA(0, 0); Afr[0][1] = LDA(0, 1);
        Afr[1][0] = LDA(1, 0); Afr[1][1] = LDA(1, 1);
        Bfr[0][0] = LDB(0, 0); Bfr[0][1] = LDB(0, 1);
        Bfr[1][0] = LDB(1, 0); Bfr[1][1] = LDB(1, 1);
        if (pf) { STAGE(t2, 0); STAGE(t2, 1); }
        __builtin_amdgcn_s_barrier();
        asm volatile("s_waitcnt lgkmcnt(0)" ::: "memory");
        __builtin_amdgcn_sched_barrier(0);
        __builtin_amdgcn_s_setprio(1);
        acc[0][0] = MF(Afr[0][0], Bfr[0][0], acc[0][0]); acc[0][0] = MF(Afr[0][1], Bfr[0][1], acc[0][0]);
        acc[0][1] = MF(Afr[0][0], Bfr[1][0], acc[0][1]); acc[0][1] = MF(Afr[0][1], Bfr[1][1], acc[0][1]);
        acc[1][0] = MF(Afr[1][0], Bfr[0][0], acc[1][0]); acc[1][0] = MF(Afr[1][1], Bfr[0][1], acc[1][0]);
        acc[1][1] = MF(Afr[1][0], Bfr[1][0], acc[1][1]); acc[1][1] = MF(Afr[1][1], Bfr[1][1], acc[1][1]);
        __builtin_amdgcn_s_setprio(0);

        // ---- phase 1
        Bfr[2][0] = LDB(2, 0); Bfr[2][1] = LDB(2, 1);
        Bfr[3][0] = LDB(3, 0); Bfr[3][1] = LDB(3, 1);
        if (pf) { STAGE(t2, 2); STAGE(t2, 3); }
        __builtin_amdgcn_s_barrier();
        asm volatile("s_waitcnt lgkmcnt(0)" ::: "memory");
        __builtin_amdgcn_sched_barrier(0);
        __builtin_amdgcn_s_setprio(1);
        acc[0][2] = MF(Afr[0][0], Bfr[2][0], acc[0][2]); acc[0][2] = MF(Afr[0][1], Bfr[2][1], acc[0][2]);
        acc[0][3] = MF(Afr[0][0], Bfr[3][0], acc[0][3]); acc[0][3] = MF(Afr[0][1], Bfr[3][1], acc[0][3]);
        acc[1][2] = MF(Afr[1][0], Bfr[2][0], acc[1][2]); acc[1][2] = MF(Afr[1][1], Bfr[2][1], acc[1][2]);
        acc[1][3] = MF(Afr[1][0], Bfr[3][0], acc[1][3]); acc[1][3] = MF(Afr[1][1], Bfr[3][1], acc[1][3]);
        __builtin_amdgcn_s_setprio(0);

        // ---- phase 2
        Afr[0][0] = LDA(2, 0); Afr[0][1] = LDA(2, 1);
        Afr[1][0] = LDA(3, 0); Afr[1][1] = LDA(3, 1);
        if (pf) STAGE(t2, 4);
        __builtin_amdgcn_s_barrier();
        asm volatile("s_waitcnt lgkmcnt(0)" ::: "memory");
        __builtin_amdgcn_sched_barrier(0);
        __builtin_amdgcn_s_setprio(1);
        acc[2][2] = MF(Afr[0][0], Bfr[2][0], acc[2][2]); acc[2][2] = MF(Afr[0][1], Bfr[2][1], acc[2][2]);
        acc[2][3] = MF(Afr[0][0], Bfr[3][0], acc[2][3]); acc[2][3] = MF(Afr[0][1], Bfr[3][1], acc[2][3]);
        acc[3][2] = MF(Afr[1][0], Bfr[2][0], acc[3][2]); acc[3][2] = MF(Afr[1][1], Bfr[2][1], acc[3][2]);
        acc[3][3] = MF(Afr[1][0], Bfr[3][0], acc[3][3]); acc[3][3] = MF(Afr[1][1], Bfr[3][1], acc[3][3]);
        __builtin_amdgcn_s_setprio(0);

        // ---- phase 3
        if (pf) STAGE(t2, 5);
        __builtin_amdgcn_s_barrier();
        __builtin_amdgcn_s_setprio(1);
        acc[2][0] = MF(Afr[0][0], Bfr[0][0], acc[2][0]); acc[2][0] = MF(Afr[0][1], Bfr[0][1], acc[2][0]);
        acc[2][1] = MF(Afr[0][0], Bfr[1][0], acc[2][1]); acc[2][1] = MF(Afr[0][1], Bfr[1][1], acc[2][1]);
        acc[3][0] = MF(Afr[1][0], Bfr[0][0], acc[3][0]); acc[3][0] = MF(Afr[1][1], Bfr[0][1], acc[3][0]);
        acc[3][1] = MF(Afr[1][0], Bfr[1][0], acc[3][1]); acc[3][1] = MF(Afr[1][1], Bfr[1][1], acc[3][1]);
        __builtin_amdgcn_s_setprio(0);
    }

    const int gr_base = bm * 128 + wr * 64;
    const int gc_base = bn * 256 + wc * 64;
#pragma unroll
    for (int m = 0; m < 4; ++m) {
        int gr0 = gr_base + (m << 4) + (hi << 2);
#pragma unroll
        for (int n = 0; n < 4; ++n) {
            int gc = gc_base + (n << 4) + lo;
            float bv = bvec[gc];
            if (EPI == 0) {
                int sec = gc / EMB;
                int rr  = gc - sec * EMB;
                int h   = rr / HD;
                int d   = rr - h * HD;
                if (sec == 2) {
                    ushort4 pk;
                    pk.x = f2bf(acc[m][n][0] + bv);
                    pk.y = f2bf(acc[m][n][1] + bv);
                    pk.z = f2bf(acc[m][n][2] + bv);
                    pk.w = f2bf(acc[m][n][3] + bv);
                    *reinterpret_cast<ushort4*>(Vo + ((size_t)h * HD + d) * S_LEN + gr0) = pk;
                } else {
#pragma unroll
                    for (int j = 0; j < 4; ++j) {
                        float vv = acc[m][n][j] + bv;
                        int s = gr0 + j;
                        if (sec == 0) Qo[((size_t)h * S_LEN + s) * DP + d] = f2bf(vv * (1.0f / 80.0f));
                        else          Ko[((size_t)h * S_LEN + s) * DP + d] = f2bf(vv);
                    }
                }
            } else {
#pragma unroll
                for (int j = 0; j < 4; ++j)
                    Co[(size_t)(gr0 + j) * Ncols + gc] = acc[m][n][j] + bv;
            }
        }
    }
}

// ---------------- flash attention, per (head, 128-row q-tile) ----------------
// R4/R11 measured-best structure. ONE new element vs R11: a REGISTER-FREE L2
// prefetch of the next tile's bias region via global_load_lds(size=4) into a
// dummy 256B/wave LDS scratch. No VGPR is written (R12's asm-load clobber bug
// is impossible); the op is vmcnt-counted and drained by the existing per-tile
// __syncthreads. 64 lanes x 64B-spaced addresses touch all 512 lines of the
// 128x256B bias block one tile ahead, so the compiler-sunk real bias loads
// hit L2 (~200cy) instead of HBM (~900cy).
__global__ __launch_bounds__(512, 4)
void attn_fwd(const ushort* __restrict__ Q, const ushort* __restrict__ K,
              const ushort* __restrict__ VT, const float* __restrict__ bias,
              const float* __restrict__ mask, ushort* __restrict__ ctx)
{
    __shared__ ushort Ks[2][64 * 96];     // 2 x 12KB, swizzled image (see stage_k)
    __shared__ ushort Vs[2][80 * 64];     // 2 x 10KB, 128B rows, XOR-swizzled
    __shared__ ushort P[8][16][72];       // 18KB
    __shared__ char   bscr[8][256];       // 2KB dummy sink for bias prefetch (total 64KB)

    const int bid = blockIdx.x;
    const int l_  = (bid & 7) * 64 + (bid >> 3);   // bijective XCD swizzle (512 % 8 == 0)
    const int h   = l_ >> 4;
    const int qb  = (l_ & 15) << 7;
    const int tid = threadIdx.x;
    const int w   = tid >> 6, lane = tid & 63;
    const int lo  = lane & 15, hi = lane >> 4;
    const int qrow = qb + (w << 4);

    const ushort* qp = Q + ((size_t)(h * S_LEN + qrow + lo)) * DP + hi * 8;
    bf16x8 qf0 = ldg8(qp), qf1 = ldg8(qp + 32), qf2 = ldg8(qp + 64);

    const char*  kg = (const char*)(K + (size_t)h * S_LEN * DP);
    const char*  vg = (const char*)(VT + (size_t)h * HD * S_LEN);
    const float* bb = bias + (size_t)(h * S_LEN + qrow + hi * 4) * S_LEN + lo;

    // per-thread bias prefetch address: line (tid) of the 128-row x 256B block
    const char* bpA = (const char*)(bias + ((size_t)h * S_LEN + qb) * S_LEN)
                      + (size_t)(tid >> 2) * 8192 + (tid & 3) * 64;

    // per-lane pre-swizzled K source offsets: LDS[r*192+y] = Kg[r][y ^ swz(r,y)]
    int offK0, offK1;
    {
        int b0 = (w << 10) + lane * 16;
        int r0 = b0 / 192, y0 = b0 - r0 * 192;
        offK0 = r0 * 192 + (y0 ^ ((y0 < 128 ? (r0 & 7) : (r0 & 3)) << 4));
        int b1 = ((w + 8) << 10) + lane * 16;
        int r1 = b1 / 192, y1 = b1 - r1 * 192;
        offK1 = r1 * 192 + (y1 ^ ((y1 < 128 ? (r1 & 7) : (r1 & 3)) << 4));
    }

    f32x4 o[5] = {};
    float l_p[4] = {0.f, 0.f, 0.f, 0.f};
    float m_r[4] = {-1e30f, -1e30f, -1e30f, -1e30f};
    float bc[4][4], bn[4][4], mn_[4];

    auto stage_k = [&](int buf, int kt) {   // 12 x 1KB chunks, swizzled source
        const char* src = kg + (size_t)kt * 192;
        gload_lds16(src + offK0, (char*)Ks[buf] + (w << 10));
        if (w < 4)
            gload_lds16(src + offK1, (char*)Ks[buf] + ((w + 8) << 10));
    };
    auto stage_v = [&](int buf, int kt) {   // 10 x 1KB chunks, pre-swizzled source
        int r0 = (w << 3) + (lane >> 3);
        int s0 = ((lane & 7) << 4) ^ ((r0 & 7) << 4);
        gload_lds16(vg + (size_t)r0 * (S_LEN * 2) + (size_t)kt * 2 + s0,
                    (char*)Vs[buf] + (w << 10));
        if (w < 2) {
            int r1 = ((w + 8) << 3) + (lane >> 3);
            int s1 = ((lane & 7) << 4) ^ ((r1 & 7) << 4);
            gload_lds16(vg + (size_t)r1 * (S_LEN * 2) + (size_t)kt * 2 + s1,
                        (char*)Vs[buf] + ((w + 8) << 10));
        }
    };
    auto bload = [&](int kt) {
#pragma unroll
        for (int n = 0; n < 4; ++n) {
            mn_[n] = mask[kt + n * 16 + lo];
#pragma unroll
            for (int j = 0; j < 4; ++j)
                bn[n][j] = __builtin_nontemporal_load(bb + (size_t)j * S_LEN + kt + n * 16);
        }
    };
    auto rotate = [&]() {
#pragma unroll
        for (int n = 0; n < 4; ++n)
#pragma unroll
            for (int j = 0; j < 4; ++j)
                bc[n][j] = bn[n][j] + mn_[n];
    };
    auto bprefetch = [&](int kt) {   // register-free L2 warm: 1 gload_lds/wave into scratch
        gload_lds4(bpA + (size_t)kt * 4, bscr[w]);
    };

    stage_k(0, 0); stage_v(0, 0); bload(0); rotate();
    __syncthreads();   // drains vmcnt(0): tile 0 staged

#pragma unroll 1
    for (int t = 0; t < 32; ++t) {
        const int kt = t << 6;
        const int cb = t & 1;
        if (t < 31) {
            bprefetch(kt + 64);   // issues at tile top; real sunk loads issue near tile bottom
            stage_k(cb ^ 1, kt + 64); stage_v(cb ^ 1, kt + 64); bload(kt + 64);
        }

        // QK^T from LDS K tile (swizzled read mirrors staged image)
        const char* tb = (const char*)Ks[cb];
        f32x4 sc[4] = {};
        __builtin_amdgcn_s_setprio(1);
#pragma unroll
        for (int n = 0; n < 4; ++n) {
            const int r  = (n << 4) + lo;
            const char* rp = tb + r * 192;
            const int s7 = (r & 7) << 4, s3 = (r & 3) << 4;
            sc[n] = __builtin_amdgcn_mfma_f32_16x16x32_bf16(qf0, *(const bf16x8*)(rp + ((hi * 16) ^ s7)),        sc[n], 0, 0, 0);
            sc[n] = __builtin_amdgcn_mfma_f32_16x16x32_bf16(qf1, *(const bf16x8*)(rp + ((64 + hi * 16) ^ s7)),   sc[n], 0, 0, 0);
            sc[n] = __builtin_amdgcn_mfma_f32_16x16x32_bf16(qf2, *(const bf16x8*)(rp + ((128 + hi * 16) ^ s3)),  sc[n], 0, 0, 0);
        }
        __builtin_amdgcn_s_setprio(0);

        // bias(+mask) from prefetched regs
#pragma unroll
        for (int n = 0; n < 4; ++n)
#pragma unroll
            for (int j = 0; j < 4; ++j)
                sc[n][j] += bc[n][j];

        // online softmax
        float tm[4];
#pragma unroll
        for (int j = 0; j < 4; ++j)
            tm[j] = fmaxf(fmaxf(sc[0][j], sc[1][j]), fmaxf(sc[2][j], sc[3][j]));
#pragma unroll
        for (int off = 1; off <= 8; off <<= 1)
#pragma unroll
            for (int j = 0; j < 4; ++j)
                tm[j] = fmaxf(tm[j], __shfl_xor(tm[j], off, 64));

        float al[4];
#pragma unroll
        for (int j = 0; j < 4; ++j) {
            float mnew = fmaxf(m_r[j], tm[j]);
            al[j] = __builtin_amdgcn_exp2f((m_r[j] - mnew) * 1.44269504f);
            m_r[j] = mnew;
            l_p[j] *= al[j];
        }
#pragma unroll
        for (int dn = 0; dn < 5; ++dn)
#pragma unroll
            for (int j = 0; j < 4; ++j)
                o[dn][j] *= al[j];
#pragma unroll
        for (int n = 0; n < 4; ++n)
#pragma unroll
            for (int j = 0; j < 4; ++j) {
                float p = __builtin_amdgcn_exp2f((sc[n][j] - m_r[j]) * 1.44269504f);
                l_p[j] += p;
                P[w][hi * 4 + j][n * 16 + lo] = f2bf(p);
            }
        asm volatile("s_waitcnt lgkmcnt(0)" ::: "memory");
        __builtin_amdgcn_sched_barrier(0);
        bf16x8 pf0 = ldg8(&P[w][lo][hi * 8]);
        bf16x8 pf1 = ldg8(&P[w][lo][32 + hi * 8]);

        // PV from LDS V tile (swizzled read)
        const char* vb_ = (const char*)Vs[cb];
        __builtin_amdgcn_s_setprio(1);
#pragma unroll
        for (int dn = 0; dn < 5; ++dn) {
            const int rv = (dn << 4) + lo;
            const char* vp = vb_ + (rv << 7);
            const int sv = (rv & 7) << 4;
            o[dn] = __builtin_amdgcn_mfma_f32_16x16x32_bf16(pf0, *(const bf16x8*)(vp + ((hi * 16) ^ sv)),      o[dn], 0, 0, 0);
            o[dn] = __builtin_amdgcn_mfma_f32_16x16x32_bf16(pf1, *(const bf16x8*)(vp + ((64 + hi * 16) ^ sv)), o[dn], 0, 0, 0);
        }
        __builtin_amdgcn_s_setprio(0);

        rotate();
        __syncthreads();   // drains vmcnt(0)+lgkmcnt(0): next tile staged, all waves done
    }

    float inv[4];
#pragma unroll
    for (int j = 0; j < 4; ++j) {
        float t = l_p[j];
        t += __shfl_xor(t, 1, 64); t += __shfl_xor(t, 2, 64);
        t += __shfl_xor(t, 4, 64); t += __shfl_xor(t, 8, 64);
        inv[j] = 1.0f / t;
    }
    ushort* cp = ctx + (size_t)(qrow + hi * 4) * EMB + h * HD + lo;
#pragma unroll
    for (int dn = 0; dn < 5; ++dn)
#pragma unroll
        for (int j = 0; j < 4; ++j)
            cp[(size_t)j * EMB + dn * 16] = f2bf(o[dn][j] * inv[j]);
}

// ---------------- host launch ----------------
extern "C" void kernel_launch(void* const* d_in, const int* in_sizes, int n_in,
                              void* d_out, int out_size, void* d_ws, size_t ws_size,
                              hipStream_t stream)
{
    const float* hs     = (const float*)d_in[0];
    const float* mask   = (const float*)d_in[1];
    const float* pbias  = (const float*)d_in[2];
    const float* attn_w = (const float*)d_in[3];
    const float* attn_b = (const float*)d_in[4];
    const float* proj_w = (const float*)d_in[5];
    const float* proj_b = (const float*)d_in[6];
    float* outp = (float*)d_out;

    char* ws = (char*)d_ws;
    ushort* hsB    = (ushort*)(ws);                   // reused as ctx
    ushort* attnWT = (ushort*)(ws + 10485760ull);     // reused as projWT
    ushort* Qb     = (ushort*)(ws + 49807360ull);
    ushort* Kb     = (ushort*)(ws + 62390272ull);
    ushort* VTb    = (ushort*)(ws + 74973184ull);
    ushort* ctx    = hsB;
    ushort* projWT = attnWT;

    cvt_f32_bf16<<<5120, 256, 0, stream>>>(hs, hsB, 1310720);
    transpose_cvt<<<dim3(7680 / 32, 2560 / 32), dim3(32, 8), 0, stream>>>(attn_w, attnWT, 2560, 7680);
    pad_zero<<<512, 256, 0, stream>>>(Qb, Kb);

    gemm8p<0><<<480, 512, 0, stream>>>(hsB, attnWT, 30, attn_b, Qb, Kb, VTb, nullptr, 0);

    attn_fwd<<<512, 512, 0, stream>>>(Qb, Kb, VTb, pbias, mask, ctx);

    transpose_cvt<<<dim3(2560 / 32, 2560 / 32), dim3(32, 8), 0, stream>>>(proj_w, projWT, 2560, 2560);

    gemm8p<1><<<160, 512, 0, stream>>>(ctx, projWT, 10, proj_b,
                                       nullptr, nullptr, nullptr, outp, 2560);
}

// Round 14
// 334.667 us; speedup vs baseline: 1.0721x; 1.0721x over previous
//
#include <hip/hip_runtime.h>
#include <stdint.h>

#define S_LEN 2048
#define EMB   2560
#define NH    32
#define HD    80
#define DP    96   // padded head dim for Q,K (3 x 32)

typedef __bf16 bf16x8 __attribute__((ext_vector_type(8)));
typedef float  f32x4  __attribute__((ext_vector_type(4)));

__device__ __forceinline__ ushort f2bf(float x) {
    union { float f; uint32_t u; } v; v.f = x;
    return (ushort)((v.u + 0x7FFFu + ((v.u >> 16) & 1u)) >> 16);
}

__device__ __forceinline__ bf16x8 ldg8(const ushort* p) {
    return *reinterpret_cast<const bf16x8*>(p);
}

__device__ __forceinline__ void gload_lds16(const void* g, void* l) {
    __builtin_amdgcn_global_load_lds((__attribute__((address_space(1))) void*)g,
                                     (__attribute__((address_space(3))) void*)l,
                                     16, 0, 0);
}

// ---------------- elementwise f32 -> bf16 ----------------
__global__ void cvt_f32_bf16(const float* __restrict__ in, ushort* __restrict__ out, int n4) {
    int i = blockIdx.x * blockDim.x + threadIdx.x;
    if (i >= n4) return;
    float4 v = reinterpret_cast<const float4*>(in)[i];
    ushort4 r;
    r.x = f2bf(v.x); r.y = f2bf(v.y); r.z = f2bf(v.z); r.w = f2bf(v.w);
    reinterpret_cast<ushort4*>(out)[i] = r;
}

// ---------------- zero the pad columns (d=80..95) of Q and K ----------------
__global__ void pad_zero(ushort* __restrict__ Qb, ushort* __restrict__ Kb) {
    int i   = blockIdx.x * blockDim.x + threadIdx.x;   // 131072 threads
    int row = i & 65535;
    ushort* base = ((i >> 16) ? Kb : Qb) + (size_t)row * DP + HD;
    uint4 z = {0, 0, 0, 0};
    *reinterpret_cast<uint4*>(base)     = z;
    *reinterpret_cast<uint4*>(base + 8) = z;
}

// ---------------- transpose f32 [R][C] -> bf16 [C][R] ----------------
__global__ void transpose_cvt(const float* __restrict__ in, ushort* __restrict__ out, int R, int C) {
    __shared__ float tile[32][33];
    const int bx = blockIdx.x << 5;
    const int by = blockIdx.y << 5;
    const int tx = threadIdx.x, ty = threadIdx.y;  // (32,8)
#pragma unroll
    for (int i = 0; i < 4; ++i)
        tile[ty + 8 * i][tx] = in[(size_t)(by + ty + 8 * i) * C + bx + tx];
    __syncthreads();
#pragma unroll
    for (int i = 0; i < 4; ++i)
        out[(size_t)(bx + ty + 8 * i) * R + by + tx] = f2bf(tile[tx][ty + 8 * i]);
}

// ================= 8-phase GEMM (shared main loop) =================
// A[M][2560] x BT[N][2560]. BM=128, BN=256, BK=64; 512 threads = 8 waves.
// 3 rotating LDS slots, prefetch distance 2 K-tiles, counted vmcnt(6).
// EPI==0: QKV scatter epilogue (N=7680). EPI==1: fp32 C + bias (proj).
#define MF(a, b, c) __builtin_amdgcn_mfma_f32_16x16x32_bf16((a), (b), (c), 0, 0, 0)

#define STAGE(kt2, j) do {                                                          \
    char* _d = Lds + ((kt2) % 3) * 49152 + ldsW[(j)];                               \
    if ((j) < 2) gload_lds16(aG + (size_t)(kt2) * 128 + srcA[(j)], _d);             \
    else         gload_lds16(bG + (size_t)(kt2) * 128 + srcB[(j) - 2], _d);         \
} while (0)

#define LDA(mi, kk) (*(const bf16x8*)(sbase + ((wr * 64 + (mi) * 16 + lo) * 128 +   \
                      ((((kk) * 64) + hi * 16) ^ ((lo & 7) << 4)))))
#define LDB(ni, kk) (*(const bf16x8*)(sbase + 16384 +                               \
                      ((wc * 64 + (ni) * 16 + lo) * 128 +                           \
                      ((((kk) * 64) + hi * 16) ^ ((lo & 7) << 4)))))

template <int EPI>
__global__ __launch_bounds__(512)
void gemm8p(const ushort* __restrict__ A, const ushort* __restrict__ BT,
            int nbn, const float* __restrict__ bvec,
            ushort* __restrict__ Qo, ushort* __restrict__ Ko, ushort* __restrict__ Vo,
            float* __restrict__ Co, int Ncols)
{
    __shared__ char Lds[3 * 49152];   // 147456 B

    const int NT  = 40;               // 2560 / 64
    const int bid = blockIdx.x;
    const int cpx = gridDim.x >> 3;   // grid % 8 == 0
    const int wg  = (bid & 7) * cpx + (bid >> 3);   // bijective XCD swizzle
    const int bm  = wg / nbn, bn = wg - bm * nbn;

    const int tid = threadIdx.x, w = tid >> 6, lane = tid & 63;
    const int lo  = lane & 15, hi = lane >> 4;
    const int wr  = w >> 2, wc = w & 3;

    const char* aG = (const char*)(A  + (size_t)bm * 128 * 2560);
    const char* bG = (const char*)(BT + (size_t)bn * 256 * 2560);

    int srcA[2], srcB[4], ldsW[6];
#pragma unroll
    for (int j = 0; j < 6; ++j) {
        int Lb = j * 8192 + w * 1024 + lane * 16;
        ldsW[j] = j * 8192 + w * 1024;
        int y = Lb & 127;
        if (j < 2) {
            int r = Lb >> 7;
            srcA[j] = r * 5120 + (y ^ ((r & 7) << 4));
        } else {
            int r = (Lb - 16384) >> 7;
            srcB[j - 2] = r * 5120 + (y ^ ((r & 7) << 4));
        }
    }

    f32x4  acc[4][4] = {};
    bf16x8 Afr[2][2], Bfr[4][2];

#pragma unroll
    for (int j = 0; j < 6; ++j) STAGE(0, j);
#pragma unroll
    for (int j = 0; j < 6; ++j) STAGE(1, j);

#pragma unroll 1
    for (int t = 0; t < NT; ++t) {
        const char* sbase = Lds + (t % 3) * 49152;
        const int  t2 = t + 2;
        const bool pf = (t2 < NT);

        if (t < NT - 1) asm volatile("s_waitcnt vmcnt(6)" ::: "memory");
        else            asm volatile("s_waitcnt vmcnt(0)" ::: "memory");
        __builtin_amdgcn_s_barrier();

        // ---- phase 0
        Afr[0][0] = LDA(0, 0); Afr[0][1] = LDA(0, 1);
        Afr[1][0] = LDA(1, 0); Afr[1][1] = LDA(1, 1);
        Bfr[0][0] = LDB(0, 0); Bfr[0][1] = LDB(0, 1);
        Bfr[1][0] = LDB(1, 0); Bfr[1][1] = LDB(1, 1);
        if (pf) { STAGE(t2, 0); STAGE(t2, 1); }
        __builtin_amdgcn_s_barrier();
        asm volatile("s_waitcnt lgkmcnt(0)" ::: "memory");
        __builtin_amdgcn_sched_barrier(0);
        __builtin_amdgcn_s_setprio(1);
        acc[0][0] = MF(Afr[0][0], Bfr[0][0], acc[0][0]); acc[0][0] = MF(Afr[0][1], Bfr[0][1], acc[0][0]);
        acc[0][1] = MF(Afr[0][0], Bfr[1][0], acc[0][1]); acc[0][1] = MF(Afr[0][1], Bfr[1][1], acc[0][1]);
        acc[1][0] = MF(Afr[1][0], Bfr[0][0], acc[1][0]); acc[1][0] = MF(Afr[1][1], Bfr[0][1], acc[1][0]);
        acc[1][1] = MF(Afr[1][0], Bfr[1][0], acc[1][1]); acc[1][1] = MF(Afr[1][1], Bfr[1][1], acc[1][1]);
        __builtin_amdgcn_s_setprio(0);

        // ---- phase 1
        Bfr[2][0] = LDB(2, 0); Bfr[2][1] = LDB(2, 1);
        Bfr[3][0] = LDB(3, 0); Bfr[3][1] = LDB(3, 1);
        if (pf) { STAGE(t2, 2); STAGE(t2, 3); }
        __builtin_amdgcn_s_barrier();
        asm volatile("s_waitcnt lgkmcnt(0)" ::: "memory");
        __builtin_amdgcn_sched_barrier(0);
        __builtin_amdgcn_s_setprio(1);
        acc[0][2] = MF(Afr[0][0], Bfr[2][0], acc[0][2]); acc[0][2] = MF(Afr[0][1], Bfr[2][1], acc[0][2]);
        acc[0][3] = MF(Afr[0][0], Bfr[3][0], acc[0][3]); acc[0][3] = MF(Afr[0][1], Bfr[3][1], acc[0][3]);
        acc[1][2] = MF(Afr[1][0], Bfr[2][0], acc[1][2]); acc[1][2] = MF(Afr[1][1], Bfr[2][1], acc[1][2]);
        acc[1][3] = MF(Afr[1][0], Bfr[3][0], acc[1][3]); acc[1][3] = MF(Afr[1][1], Bfr[3][1], acc[1][3]);
        __builtin_amdgcn_s_setprio(0);

        // ---- phase 2
        Afr[0][0] = LDA(2, 0); Afr[0][1] = LDA(2, 1);
        Afr[1][0] = LDA(3, 0); Afr[1][1] = LDA(3, 1);
        if (pf) STAGE(t2, 4);
        __builtin_amdgcn_s_barrier();
        asm volatile("s_waitcnt lgkmcnt(0)" ::: "memory");
        __builtin_amdgcn_sched_barrier(0);
        __builtin_amdgcn_s_setprio(1);
        acc[2][2] = MF(Afr[0][0], Bfr[2][0], acc[2][2]); acc[2][2] = MF(Afr[0][1], Bfr[2][1], acc[2][2]);
        acc[2][3] = MF(Afr[0][0], Bfr[3][0], acc[2][3]); acc[2][3] = MF(Afr[0][1], Bfr[3][1], acc[2][3]);
        acc[3][2] = MF(Afr[1][0], Bfr[2][0], acc[3][2]); acc[3][2] = MF(Afr[1][1], Bfr[2][1], acc[3][2]);
        acc[3][3] = MF(Afr[1][0], Bfr[3][0], acc[3][3]); acc[3][3] = MF(Afr[1][1], Bfr[3][1], acc[3][3]);
        __builtin_amdgcn_s_setprio(0);

        // ---- phase 3
        if (pf) STAGE(t2, 5);
        __builtin_amdgcn_s_barrier();
        __builtin_amdgcn_s_setprio(1);
        acc[2][0] = MF(Afr[0][0], Bfr[0][0], acc[2][0]); acc[2][0] = MF(Afr[0][1], Bfr[0][1], acc[2][0]);
        acc[2][1] = MF(Afr[0][0], Bfr[1][0], acc[2][1]); acc[2][1] = MF(Afr[0][1], Bfr[1][1], acc[2][1]);
        acc[3][0] = MF(Afr[1][0], Bfr[0][0], acc[3][0]); acc[3][0] = MF(Afr[1][1], Bfr[0][1], acc[3][0]);
        acc[3][1] = MF(Afr[1][0], Bfr[1][0], acc[3][1]); acc[3][1] = MF(Afr[1][1], Bfr[1][1], acc[3][1]);
        __builtin_amdgcn_s_setprio(0);
    }

    const int gr_base = bm * 128 + wr * 64;
    const int gc_base = bn * 256 + wc * 64;
#pragma unroll
    for (int m = 0; m < 4; ++m) {
        int gr0 = gr_base + (m << 4) + (hi << 2);
#pragma unroll
        for (int n = 0; n < 4; ++n) {
            int gc = gc_base + (n << 4) + lo;
            float bv = bvec[gc];
            if (EPI == 0) {
                int sec = gc / EMB;
                int rr  = gc - sec * EMB;
                int h   = rr / HD;
                int d   = rr - h * HD;
                if (sec == 2) {
                    ushort4 pk;
                    pk.x = f2bf(acc[m][n][0] + bv);
                    pk.y = f2bf(acc[m][n][1] + bv);
                    pk.z = f2bf(acc[m][n][2] + bv);
                    pk.w = f2bf(acc[m][n][3] + bv);
                    *reinterpret_cast<ushort4*>(Vo + ((size_t)h * HD + d) * S_LEN + gr0) = pk;
                } else {
#pragma unroll
                    for (int j = 0; j < 4; ++j) {
                        float vv = acc[m][n][j] + bv;
                        int s = gr0 + j;
                        if (sec == 0) Qo[((size_t)h * S_LEN + s) * DP + d] = f2bf(vv * (1.0f / 80.0f));
                        else          Ko[((size_t)h * S_LEN + s) * DP + d] = f2bf(vv);
                    }
                }
            } else {
#pragma unroll
                for (int j = 0; j < 4; ++j)
                    Co[(size_t)(gr0 + j) * Ncols + gc] = acc[m][n][j] + bv;
            }
        }
    }
}

// ---------------- flash attention, per (head, 128-row q-tile) ----------------
// R4/R11 measured-best configuration (334.8 us total), byte-exact revert.
// 8 waves; K/V LDS double-buffered, staged 1 tile ahead via global_load_lds;
// bias+mask in registers with compiler-scheduled (sunk) loads; per-tile
// __syncthreads drain. (512,4): the 64-VGPR sunk-load schedule beat every
// hoisted/counted-vmcnt/128-reg/L2-prefetch variant tried in R5-R13 — attn is
// bandwidth-pattern-bound (~4.2 TB/s effective on the 64B-granular bias
// stream); added requests (R13) or schedule pinning (R5-R10) only regress.
__global__ __launch_bounds__(512, 4)
void attn_fwd(const ushort* __restrict__ Q, const ushort* __restrict__ K,
              const ushort* __restrict__ VT, const float* __restrict__ bias,
              const float* __restrict__ mask, ushort* __restrict__ ctx)
{
    __shared__ ushort Ks[2][64 * 96];     // 2 x 12KB, swizzled image (see stage_k)
    __shared__ ushort Vs[2][80 * 64];     // 2 x 10KB, 128B rows, XOR-swizzled
    __shared__ ushort P[8][16][72];       // 18KB

    const int bid = blockIdx.x;
    const int l_  = (bid & 7) * 64 + (bid >> 3);   // bijective XCD swizzle (512 % 8 == 0)
    const int h   = l_ >> 4;
    const int qb  = (l_ & 15) << 7;
    const int tid = threadIdx.x;
    const int w   = tid >> 6, lane = tid & 63;
    const int lo  = lane & 15, hi = lane >> 4;
    const int qrow = qb + (w << 4);

    const ushort* qp = Q + ((size_t)(h * S_LEN + qrow + lo)) * DP + hi * 8;
    bf16x8 qf0 = ldg8(qp), qf1 = ldg8(qp + 32), qf2 = ldg8(qp + 64);

    const char*  kg = (const char*)(K + (size_t)h * S_LEN * DP);
    const char*  vg = (const char*)(VT + (size_t)h * HD * S_LEN);
    const float* bb = bias + (size_t)(h * S_LEN + qrow + hi * 4) * S_LEN + lo;

    // per-lane pre-swizzled K source offsets: LDS[r*192+y] = Kg[r][y ^ swz(r,y)]
    int offK0, offK1;
    {
        int b0 = (w << 10) + lane * 16;
        int r0 = b0 / 192, y0 = b0 - r0 * 192;
        offK0 = r0 * 192 + (y0 ^ ((y0 < 128 ? (r0 & 7) : (r0 & 3)) << 4));
        int b1 = ((w + 8) << 10) + lane * 16;
        int r1 = b1 / 192, y1 = b1 - r1 * 192;
        offK1 = r1 * 192 + (y1 ^ ((y1 < 128 ? (r1 & 7) : (r1 & 3)) << 4));
    }

    f32x4 o[5] = {};
    float l_p[4] = {0.f, 0.f, 0.f, 0.f};
    float m_r[4] = {-1e30f, -1e30f, -1e30f, -1e30f};
    float bc[4][4], bn[4][4], mn_[4];

    auto stage_k = [&](int buf, int kt) {   // 12 x 1KB chunks, swizzled source
        const char* src = kg + (size_t)kt * 192;
        gload_lds16(src + offK0, (char*)Ks[buf] + (w << 10));
        if (w < 4)
            gload_lds16(src + offK1, (char*)Ks[buf] + ((w + 8) << 10));
    };
    auto stage_v = [&](int buf, int kt) {   // 10 x 1KB chunks, pre-swizzled source
        int r0 = (w << 3) + (lane >> 3);
        int s0 = ((lane & 7) << 4) ^ ((r0 & 7) << 4);
        gload_lds16(vg + (size_t)r0 * (S_LEN * 2) + (size_t)kt * 2 + s0,
                    (char*)Vs[buf] + (w << 10));
        if (w < 2) {
            int r1 = ((w + 8) << 3) + (lane >> 3);
            int s1 = ((lane & 7) << 4) ^ ((r1 & 7) << 4);
            gload_lds16(vg + (size_t)r1 * (S_LEN * 2) + (size_t)kt * 2 + s1,
                        (char*)Vs[buf] + ((w + 8) << 10));
        }
    };
    auto bload = [&](int kt) {
#pragma unroll
        for (int n = 0; n < 4; ++n) {
            mn_[n] = mask[kt + n * 16 + lo];
#pragma unroll
            for (int j = 0; j < 4; ++j)
                bn[n][j] = __builtin_nontemporal_load(bb + (size_t)j * S_LEN + kt + n * 16);
        }
    };
    auto rotate = [&]() {
#pragma unroll
        for (int n = 0; n < 4; ++n)
#pragma unroll
            for (int j = 0; j < 4; ++j)
                bc[n][j] = bn[n][j] + mn_[n];
    };

    stage_k(0, 0); stage_v(0, 0); bload(0); rotate();
    __syncthreads();   // drains vmcnt(0): tile 0 staged

#pragma unroll 1
    for (int t = 0; t < 32; ++t) {
        const int kt = t << 6;
        const int cb = t & 1;
        if (t < 31) { stage_k(cb ^ 1, kt + 64); stage_v(cb ^ 1, kt + 64); bload(kt + 64); }

        // QK^T from LDS K tile (swizzled read mirrors staged image)
        const char* tb = (const char*)Ks[cb];
        f32x4 sc[4] = {};
        __builtin_amdgcn_s_setprio(1);
#pragma unroll
        for (int n = 0; n < 4; ++n) {
            const int r  = (n << 4) + lo;
            const char* rp = tb + r * 192;
            const int s7 = (r & 7) << 4, s3 = (r & 3) << 4;
            sc[n] = __builtin_amdgcn_mfma_f32_16x16x32_bf16(qf0, *(const bf16x8*)(rp + ((hi * 16) ^ s7)),        sc[n], 0, 0, 0);
            sc[n] = __builtin_amdgcn_mfma_f32_16x16x32_bf16(qf1, *(const bf16x8*)(rp + ((64 + hi * 16) ^ s7)),   sc[n], 0, 0, 0);
            sc[n] = __builtin_amdgcn_mfma_f32_16x16x32_bf16(qf2, *(const bf16x8*)(rp + ((128 + hi * 16) ^ s3)),  sc[n], 0, 0, 0);
        }
        __builtin_amdgcn_s_setprio(0);

        // bias(+mask) from prefetched regs
#pragma unroll
        for (int n = 0; n < 4; ++n)
#pragma unroll
            for (int j = 0; j < 4; ++j)
                sc[n][j] += bc[n][j];

        // online softmax
        float tm[4];
#pragma unroll
        for (int j = 0; j < 4; ++j)
            tm[j] = fmaxf(fmaxf(sc[0][j], sc[1][j]), fmaxf(sc[2][j], sc[3][j]));
#pragma unroll
        for (int off = 1; off <= 8; off <<= 1)
#pragma unroll
            for (int j = 0; j < 4; ++j)
                tm[j] = fmaxf(tm[j], __shfl_xor(tm[j], off, 64));

        float al[4];
#pragma unroll
        for (int j = 0; j < 4; ++j) {
            float mnew = fmaxf(m_r[j], tm[j]);
            al[j] = __builtin_amdgcn_exp2f((m_r[j] - mnew) * 1.44269504f);
            m_r[j] = mnew;
            l_p[j] *= al[j];
        }
#pragma unroll
        for (int dn = 0; dn < 5; ++dn)
#pragma unroll
            for (int j = 0; j < 4; ++j)
                o[dn][j] *= al[j];
#pragma unroll
        for (int n = 0; n < 4; ++n)
#pragma unroll
            for (int j = 0; j < 4; ++j) {
                float p = __builtin_amdgcn_exp2f((sc[n][j] - m_r[j]) * 1.44269504f);
                l_p[j] += p;
                P[w][hi * 4 + j][n * 16 + lo] = f2bf(p);
            }
        asm volatile("s_waitcnt lgkmcnt(0)" ::: "memory");
        __builtin_amdgcn_sched_barrier(0);
        bf16x8 pf0 = ldg8(&P[w][lo][hi * 8]);
        bf16x8 pf1 = ldg8(&P[w][lo][32 + hi * 8]);

        // PV from LDS V tile (swizzled read)
        const char* vb_ = (const char*)Vs[cb];
        __builtin_amdgcn_s_setprio(1);
#pragma unroll
        for (int dn = 0; dn < 5; ++dn) {
            const int rv = (dn << 4) + lo;
            const char* vp = vb_ + (rv << 7);
            const int sv = (rv & 7) << 4;
            o[dn] = __builtin_amdgcn_mfma_f32_16x16x32_bf16(pf0, *(const bf16x8*)(vp + ((hi * 16) ^ sv)),      o[dn], 0, 0, 0);
            o[dn] = __builtin_amdgcn_mfma_f32_16x16x32_bf16(pf1, *(const bf16x8*)(vp + ((64 + hi * 16) ^ sv)), o[dn], 0, 0, 0);
        }
        __builtin_amdgcn_s_setprio(0);

        rotate();
        __syncthreads();   // drains vmcnt(0)+lgkmcnt(0): next tile staged, all waves done
    }

    float inv[4];
#pragma unroll
    for (int j = 0; j < 4; ++j) {
        float t = l_p[j];
        t += __shfl_xor(t, 1, 64); t += __shfl_xor(t, 2, 64);
        t += __shfl_xor(t, 4, 64); t += __shfl_xor(t, 8, 64);
        inv[j] = 1.0f / t;
    }
    ushort* cp = ctx + (size_t)(qrow + hi * 4) * EMB + h * HD + lo;
#pragma unroll
    for (int dn = 0; dn < 5; ++dn)
#pragma unroll
        for (int j = 0; j < 4; ++j)
            cp[(size_t)j * EMB + dn * 16] = f2bf(o[dn][j] * inv[j]);
}

// ---------------- host launch ----------------
extern "C" void kernel_launch(void* const* d_in, const int* in_sizes, int n_in,
                              void* d_out, int out_size, void* d_ws, size_t ws_size,
                              hipStream_t stream)
{
    const float* hs     = (const float*)d_in[0];
    const float* mask   = (const float*)d_in[1];
    const float* pbias  = (const float*)d_in[2];
    const float* attn_w = (const float*)d_in[3];
    const float* attn_b = (const float*)d_in[4];
    const float* proj_w = (const float*)d_in[5];
    const float* proj_b = (const float*)d_in[6];
    float* outp = (float*)d_out;

    char* ws = (char*)d_ws;
    ushort* hsB    = (ushort*)(ws);                   // reused as ctx
    ushort* attnWT = (ushort*)(ws + 10485760ull);     // reused as projWT
    ushort* Qb     = (ushort*)(ws + 49807360ull);
    ushort* Kb     = (ushort*)(ws + 62390272ull);
    ushort* VTb    = (ushort*)(ws + 74973184ull);
    ushort* ctx    = hsB;
    ushort* projWT = attnWT;

    cvt_f32_bf16<<<5120, 256, 0, stream>>>(hs, hsB, 1310720);
    transpose_cvt<<<dim3(7680 / 32, 2560 / 32), dim3(32, 8), 0, stream>>>(attn_w, attnWT, 2560, 7680);
    pad_zero<<<512, 256, 0, stream>>>(Qb, Kb);

    gemm8p<0><<<480, 512, 0, stream>>>(hsB, attnWT, 30, attn_b, Qb, Kb, VTb, nullptr, 0);

    attn_fwd<<<512, 512, 0, stream>>>(Qb, Kb, VTb, pbias, mask, ctx);

    transpose_cvt<<<dim3(2560 / 32, 2560 / 32), dim3(32, 8), 0, stream>>>(proj_w, projWT, 2560, 2560);

    gemm8p<1><<<160, 512, 0, stream>>>(ctx, projWT, 10, proj_b,
                                       nullptr, nullptr, nullptr, outp, 2560);
}